// Round 8
// baseline (116.660 us; speedup 1.0000x reference)
//
#include <hip/hip_runtime.h>

// Round 8 = R3 kernel VERBATIM (best measured: bench 107.9, GEMM ~27.5us)
// + a pure-read bandwidth probe over the 64 MB weight tensor, launched after.
// Purpose: measure the actual achievable streaming-read floor for exactly the
// bytes the GEMM must move (no such number exists in any round's counters).
// probe dur = bench_R8 - bench_R3 - launch overhead; if >41.5us it surfaces
// in the top-5 counter table with its own FETCH_SIZE (L3-warm detection).

constexpr int BATCH  = 2048;
constexpr int NAGENT = 64;
constexpr int IN_F   = 512;
constexpr int OUT_F  = 512;

constexpr int BN  = 128;        // block n-tile
constexpr int MCH = 64;         // m rows per chunk
constexpr int XS  = IN_F + 8;   // X LDS stride in bf16 elems (520)

typedef __attribute__((ext_vector_type(8))) short short8;     // bf16 A/B frag (4 VGPRs)
typedef __attribute__((ext_vector_type(4))) float f32x4;      // fp32 C/D frag
typedef __attribute__((ext_vector_type(4))) unsigned int u32x4;

__device__ inline unsigned rnd_bf(float f) {
  unsigned u = __float_as_uint(f);
  return u + 0x7FFFu + ((u >> 16) & 1u);   // RTN, result in high 16 bits
}
__device__ inline unsigned pk_bf(float lo, float hi) {
  return (rnd_bf(lo) >> 16) | (rnd_bf(hi) & 0xFFFF0000u);
}

__global__ __launch_bounds__(1024, 4) void agent_linear_mfma2(
    const int*   __restrict__ which,
    const float* __restrict__ x,
    const float* __restrict__ weight,
    const float* __restrict__ bias,
    float*       __restrict__ out) {
  const int tid   = threadIdx.x;
  const int lane  = tid & 63;
  const int wid   = tid >> 6;        // 0..15
  const int w8    = wid & 7;         // n-wave within BN
  const int kh    = wid >> 3;        // k-half: 0 or 1
  const int agent = blockIdx.y;
  const int obase = blockIdx.x * BN;

  __shared__ int rowlist_s[BATCH];                       // 8 KB
  __shared__ int wsum_s[16];
  __shared__ __align__(16) unsigned short Xs[MCH * XS];  // 65 KB bf16
  __shared__ float Rs[8][MCH][17];                       // 34 KB, k-half partials

  // ---- stable compaction: rows with which[i]==agent, ascending ----
  int2 v = ((const int2*)which)[tid];                    // 2 vals/thread, 1024 threads
  int lc = (v.x == agent) + (v.y == agent);
  int s = lc;
#pragma unroll
  for (int off = 1; off < 64; off <<= 1) {
    int t = __shfl_up(s, off);
    if (lane >= off) s += t;
  }
  if (lane == 63) wsum_s[wid] = s;
  __syncthreads();
  int base = 0, count = 0;
#pragma unroll
  for (int w = 0; w < 16; ++w) {
    int ws = wsum_s[w];
    if (w < wid) base += ws;
    count += ws;
  }
  {
    int pos = base + s - lc;
    if (v.x == agent) rowlist_s[pos++] = 2 * tid;
    if (v.y == agent) rowlist_s[pos]   = 2 * tid + 1;
  }

  const int nl = lane & 15;      // n within frag / m within A-frag
  const int kq = lane >> 4;      // k-quad 0..3

  const float* wp = weight + ((size_t)(agent * OUT_F + obase + w8 * 16 + nl)) * IN_F
                  + kh * 256 + kq * 8;
  const float  bv = bias[agent * OUT_F + obase + w8 * 16 + nl];

  for (int m0 = 0; m0 < count; m0 += MCH) {
    const int mcount = min(MCH, count - m0);
    __syncthreads();   // rowlist ready / prior iter's Xs+Rs reads done

    // ---- stage X chunk: 64 rows x 512 k as bf16 ----
#pragma unroll
    for (int t = 0; t < 8; ++t) {
      int idx = t * 1024 + tid;
      int r   = idx >> 7;          // 0..63
      int c4  = idx & 127;         // float4 column
      uint2 w2 = {0u, 0u};
      if (r < mcount) {
        float4 xv = *(const float4*)(x + (size_t)rowlist_s[m0 + r] * IN_F + c4 * 4);
        w2.x = pk_bf(xv.x, xv.y);
        w2.y = pk_bf(xv.z, xv.w);
      }
      *(uint2*)&Xs[r * XS + c4 * 4] = w2;
    }
    __syncthreads();

    // ---- barrier-free K-loop over this wave's 256-k half ----
    f32x4 acc[4] = {{0.f,0.f,0.f,0.f},{0.f,0.f,0.f,0.f},
                    {0.f,0.f,0.f,0.f},{0.f,0.f,0.f,0.f}};
    const int kbase = kh * 256;
    float4 pa[2], pb[2];
    pa[0] = *(const float4*)(wp);      pb[0] = *(const float4*)(wp + 4);
    pa[1] = *(const float4*)(wp + 32); pb[1] = *(const float4*)(wp + 36);
#pragma unroll
    for (int k = 0; k < 8; ++k) {
      float4 c0 = pa[k & 1], c1 = pb[k & 1];
      if (k + 2 < 8) {
        pa[k & 1] = *(const float4*)(wp + (k + 2) * 32);
        pb[k & 1] = *(const float4*)(wp + (k + 2) * 32 + 4);
      }
      u32x4 q;
      q[0] = pk_bf(c0.x, c0.y); q[1] = pk_bf(c0.z, c0.w);
      q[2] = pk_bf(c1.x, c1.y); q[3] = pk_bf(c1.z, c1.w);
      short8 bf = __builtin_bit_cast(short8, q);
#pragma unroll
      for (int i = 0; i < 4; ++i) {
        short8 af = *(const short8*)&Xs[(i * 16 + nl) * XS + kbase + k * 32 + kq * 8];
        acc[i] = __builtin_amdgcn_mfma_f32_16x16x32_bf16(af, bf, acc[i], 0, 0, 0);
      }
    }

    // ---- cross-k-half reduction: upper waves park partials in LDS ----
    if (kh == 1) {
#pragma unroll
      for (int i = 0; i < 4; ++i)
#pragma unroll
        for (int r = 0; r < 4; ++r)
          Rs[w8][i * 16 + kq * 4 + r][nl] = acc[i][r];
    }
    __syncthreads();

    // ---- epilogue by lower waves: D row=(lane>>4)*4+reg, col=lane&15 ----
    if (kh == 0) {
#pragma unroll
      for (int i = 0; i < 4; ++i) {
#pragma unroll
        for (int r = 0; r < 4; ++r) {
          int m = i * 16 + kq * 4 + r;
          if (m < mcount) {
            out[(size_t)rowlist_s[m0 + m] * OUT_F + obase + w8 * 16 + nl] =
                acc[i][r] + Rs[w8][m][nl] + bv;
          }
        }
      }
    }
  }
}

// ---- pure-read probe: fully-coalesced float4 sweep of all 64 MB of weight ----
// 1024 blocks x 256 thr; block b covers a contiguous 64 KB slab; per iter the
// block reads 4 KB contiguous (256 lanes x 16 B); 16 independent loads/thread.
__global__ __launch_bounds__(256) void w_read_probe(
    const float4* __restrict__ w, float* __restrict__ sink) {
  const float4* p = w + (size_t)blockIdx.x * 4096 + threadIdx.x;
  float4 a = {0.f, 0.f, 0.f, 0.f};
#pragma unroll
  for (int i = 0; i < 16; ++i) {
    float4 v = p[i * 256];
    a.x += v.x; a.y += v.y; a.z += v.z; a.w += v.w;
  }
  sink[blockIdx.x * 256 + threadIdx.x] = a.x + a.y + a.z + a.w;
}

extern "C" void kernel_launch(void* const* d_in, const int* in_sizes, int n_in,
                              void* d_out, int out_size, void* d_ws, size_t ws_size,
                              hipStream_t stream) {
  const int*   which = (const int*)d_in[0];
  const float* x     = (const float*)d_in[1];
  const float* w     = (const float*)d_in[2];
  const float* b     = (const float*)d_in[3];
  float*       out   = (float*)d_out;

  // real kernel first (same cache state as R3), probe after
  agent_linear_mfma2<<<dim3(OUT_F / BN, NAGENT), dim3(1024), 0, stream>>>(
      which, x, w, b, out);
  w_read_probe<<<dim3(1024), dim3(256), 0, stream>>>(
      (const float4*)w, (float*)d_ws);
}